// Round 4
// baseline (879.103 us; speedup 1.0000x reference)
//
#include <hip/hip_runtime.h>
#include <hip/hip_bf16.h>

typedef unsigned short u16;
typedef __attribute__((ext_vector_type(4))) float f32x4;
typedef __attribute__((ext_vector_type(8))) short bf16x8;

#define BZ 64
#define LSEQ 2048
#define DDIM 512
#define UDIM 512
#define ADIM 512
#define VOC 32000
#define EDIM 256

__device__ __forceinline__ u16 f2bf(float f) {
    union { float f; unsigned int u; } v; v.f = f;
    unsigned int u = v.u;
    return (u16)((u + 0x7FFFu + ((u >> 16) & 1u)) >> 16);
}

__device__ __forceinline__ float fast_tanh(float x) {
    x = fminf(fmaxf(x, -15.f), 15.f);
    float e = __expf(2.f * x);
    return (e - 1.f) * __frcp_rn(e + 1.f);
}

__device__ __forceinline__ float fast_sig(float x) {
    return 1.f / (1.f + __expf(-x));
}

// ---------------- zero accumulators (contiguous region) ----------------
__global__ void zero_k(float4* p, int n) {
    int i = blockIdx.x * 256 + threadIdx.x;
    if (i < n) { float4 z; z.x = z.y = z.z = z.w = 0.f; p[i] = z; }
}

// ---------------- multi-job tiled transpose + fp32->bf16 pack ----------------
#define MAXTJ 16
struct TJob { const float* src; u16* dst; int R, C, ld, tileEnd; };
struct TArgs { TJob j[MAXTJ]; int nj; };

__global__ __launch_bounds__(256) void transpose_pack(TArgs a) {
    __shared__ float ts[32][33];
    int bid = blockIdx.x;
    int ji = 0;
    while (bid >= a.j[ji].tileEnd) ji++;
    int tstart = ji ? a.j[ji - 1].tileEnd : 0;
    int local = bid - tstart;
    TJob J = a.j[ji];
    int tilesC = J.C >> 5;
    int tr = local / tilesC, tc = local - tr * tilesC;
    int r0 = tr << 5, c0 = tc << 5;
    int t = threadIdx.x, col = t & 31, row0 = t >> 5;
    #pragma unroll
    for (int i = 0; i < 4; i++) {
        int r = row0 + i * 8;
        ts[r][col] = J.src[(size_t)(r0 + r) * J.C + c0 + col];
    }
    __syncthreads();
    #pragma unroll
    for (int i = 0; i < 4; i++) {
        int crow = row0 + i * 8;
        J.dst[(size_t)(c0 + crow) * J.ld + r0 + col] = f2bf(ts[col][crow]);
    }
}

// ---------------- pack prev_target + prev_hidden to bf16 ----------------
__global__ void pack_misc(const float* __restrict__ pt, const float* __restrict__ ph,
                          u16* __restrict__ ptb, u16* __restrict__ phb) {
    int idx = blockIdx.x * 256 + threadIdx.x;
    if (idx < BZ * VOC) ptb[idx] = f2bf(pt[idx]);
    int i2 = idx - BZ * VOC;
    if (i2 >= 0 && i2 < BZ * UDIM) phb[i2] = f2bf(ph[i2]);
}

// ---------------- prep: featbf[row][0..511]=bf16(feat), [512..575]=bf16(conv) ----------------
__global__ __launch_bounds__(256) void prep_feat_k(
    const float* __restrict__ feat, const float* __restrict__ Bm,
    const float* __restrict__ Qk, u16* __restrict__ featbf)
{
    __shared__ float qs[448];
    __shared__ float bwin[72];
    int t = threadIdx.x;
    int row0 = blockIdx.x * 64;
    int b = row0 >> 11, l0 = row0 & 2047;
    if (t < 448) qs[t] = Qk[t];
    if (t < 70) { int l = l0 - 3 + t; bwin[t] = (l >= 0 && l < LSEQ) ? Bm[b * LSEQ + l] : 0.f; }
    __syncthreads();
    #pragma unroll
    for (int it = 0; it < 8; it++) {
        int r = it * 8 + (t >> 5), c = (t & 31) * 16;
        const float* p = feat + (size_t)(row0 + r) * DDIM + c;
        float4 a0 = *(const float4*)p, a1 = *(const float4*)(p + 4),
               a2 = *(const float4*)(p + 8), a3 = *(const float4*)(p + 12);
        u16 u[16] = { f2bf(a0.x), f2bf(a0.y), f2bf(a0.z), f2bf(a0.w),
                      f2bf(a1.x), f2bf(a1.y), f2bf(a1.z), f2bf(a1.w),
                      f2bf(a2.x), f2bf(a2.y), f2bf(a2.z), f2bf(a2.w),
                      f2bf(a3.x), f2bf(a3.y), f2bf(a3.z), f2bf(a3.w) };
        u16* dst = featbf + (size_t)(row0 + r) * 576 + c;
        *(uint4*)dst = *(uint4*)u;
        *(uint4*)(dst + 8) = *(uint4*)(u + 8);
    }
    {
        int r = t >> 2, c = (t & 3) * 16;
        float s[16];
        #pragma unroll
        for (int j = 0; j < 16; j++) s[j] = 0.f;
        #pragma unroll
        for (int w7 = 0; w7 < 7; w7++) {
            float bv = bwin[r + w7];
            #pragma unroll
            for (int j = 0; j < 16; j++) s[j] += bv * qs[w7 * 64 + c + j];
        }
        u16 u[16];
        #pragma unroll
        for (int j = 0; j < 16; j++) u[j] = f2bf(s[j]);
        u16* dst = featbf + (size_t)(row0 + r) * 576 + 512 + c;
        *(uint4*)dst = *(uint4*)u;
        *(uint4*)(dst + 8) = *(uint4*)(u + 8);
    }
}

// ---------------- batched small GEMM: 64(M) x 64(N) tiles ----------------
// A-modes: 0 = bf16 memory; 1 = gen [Ey|h|ctx]; 2 = gen [Ey|sig(rtp)*h];
//          3 = gen [ht|ctx] (computes ht from ztp/hcp/ccz/biases, side-writes ht_out on n0==0)
// epi: 0 = atomicAdd fp32; 1 = store fp32; 2 = store f2bf(acc + Ey) to (u16*)C
#define MAXGJ 4
struct GJob { const u16* A; const u16* Bt; float* C;
              int ldA, ldB, ldC, nT, ckPer, ckTot, tileEnd, koff, mode, epi; };
struct GAux { const float *Ey, *h, *ctx, *rtp, *ztp, *hcp, *ccz, *bwyh, *burh; float* ht_out; };
struct GArgs { GJob j[MAXGJ]; GAux x; };

__global__ __launch_bounds__(256) void gemm_batch_k(GArgs ga) {
    __shared__ u16 As[64 * 40];
    __shared__ u16 Bs[64 * 40];
    int bid = blockIdx.x, ji = 0;
    while (bid >= ga.j[ji].tileEnd) ji++;
    GJob J = ga.j[ji];
    GAux x = ga.x;
    int local = bid - (ji ? ga.j[ji - 1].tileEnd : 0);
    int nti = local % J.nT, ksi = local / J.nT;
    int n0 = nti * 64;
    int ck0 = ksi * J.ckPer;
    int ckEnd = ck0 + J.ckPer; if (ckEnd > J.ckTot) ckEnd = J.ckTot;
    int tid = threadIdx.x, w = tid >> 6, lane = tid & 63, q = lane >> 4, cc = lane & 15;
    int wrow = lane >> 2, wseg = lane & 3;
    int m = w * 16 + wrow;                 // staged A row (0..63)
    f32x4 acc[4];
    #pragma unroll
    for (int mt = 0; mt < 4; mt++) acc[mt] = (f32x4)0.f;
    const u16* Ab = (J.mode == 0) ? (J.A + (size_t)m * J.ldA + wseg * 8) : nullptr;
    const u16* Bb = J.Bt + (size_t)(n0 + m) * J.ldB + wseg * 8;
    for (int ck = ck0; ck < ckEnd; ck++) {
        int k0 = ck * 32;
        if (J.mode == 0) {
            *(uint4*)&As[m * 40 + wseg * 8] = *(const uint4*)(Ab + k0);
        } else {
            int cbase = J.koff + k0 + wseg * 8;
            u16 gen[8];
            #pragma unroll
            for (int jj = 0; jj < 8; jj++) {
                int c = cbase + jj;
                float v;
                if (J.mode == 1) {
                    v = (c < 256) ? x.Ey[m * 256 + c]
                      : (c < 768) ? x.h[m * 512 + c - 256]
                                  : x.ctx[m * 512 + c - 768];
                } else if (J.mode == 2) {
                    if (c < 256) v = x.Ey[m * 256 + c];
                    else {
                        int u = c - 256;
                        v = fast_sig(x.rtp[m * 512 + u]) * x.h[m * 512 + u];
                    }
                } else {
                    if (c < 512) {
                        int u = c;
                        float z = fast_sig(x.ztp[m * 512 + u]);
                        float hc = tanhf(x.hcp[m * 512 + u] + x.ccz[m * 512 + u]
                                         + x.bwyh[u] + x.burh[u]);
                        v = (1.f - z) * x.h[m * 512 + u] + z * hc;
                        if (n0 == 0) x.ht_out[m * 512 + u] = v;
                    } else {
                        v = x.ctx[m * 512 + c - 512];
                    }
                }
                gen[jj] = f2bf(v);
            }
            *(uint4*)&As[m * 40 + wseg * 8] = *(uint4*)gen;
        }
        *(uint4*)&Bs[m * 40 + wseg * 8] = *(const uint4*)(Bb + k0);
        __syncthreads();
        bf16x8 af[4];
        #pragma unroll
        for (int mt = 0; mt < 4; mt++)
            af[mt] = *(const bf16x8*)&As[(mt * 16 + cc) * 40 + q * 8];
        bf16x8 bfr = *(const bf16x8*)&Bs[(w * 16 + cc) * 40 + q * 8];
        #pragma unroll
        for (int mt = 0; mt < 4; mt++)
            acc[mt] = __builtin_amdgcn_mfma_f32_16x16x32_bf16(af[mt], bfr, acc[mt], 0, 0, 0);
        __syncthreads();
    }
    #pragma unroll
    for (int mt = 0; mt < 4; mt++) {
        #pragma unroll
        for (int rr = 0; rr < 4; rr++) {
            int mm = mt * 16 + q * 4 + rr, n = n0 + w * 16 + cc;
            float v = acc[mt][rr];
            if (J.epi == 0) atomicAdd(&J.C[(size_t)mm * J.ldC + n], v);
            else if (J.epi == 1) J.C[(size_t)mm * J.ldC + n] = v;
            else ((u16*)J.C)[(size_t)mm * J.ldC + n] = f2bf(v + x.Ey[mm * 256 + n]);
        }
    }
}

// ---------------- attention GEMM (128x128, padded LDS, XCD swizzle) ----------------
__global__ __launch_bounds__(256) void attn_gemm_k(
    const u16* __restrict__ featbf, const u16* __restrict__ Wt,
    const float* __restrict__ hWa, const float* __restrict__ Va,
    float* __restrict__ e)
{
    __shared__ u16 As[128 * 40];
    __shared__ u16 Bs[128 * 40];
    // XCD swizzle: the 4 col-tiles of one row-tile land on the same XCD, adjacent in order.
    int bid = blockIdx.x;
    int job = (bid & 7) * 512 + (bid >> 3);
    int row0 = (job >> 2) * 128;
    int col0 = (job & 3) * 128;
    int b = row0 >> 11;
    int tid = threadIdx.x, w = tid >> 6, lane = tid & 63, q = lane >> 4, cc = lane & 15;
    int wrow = lane >> 2, wseg = lane & 3;
    int rh = w & 1, ch = w >> 1;
    f32x4 acc[4][4];
    #pragma unroll
    for (int mt = 0; mt < 4; mt++)
        #pragma unroll
        for (int nt = 0; nt < 4; nt++) acc[mt][nt] = (f32x4)0.f;
    const u16* Abase = featbf + (size_t)row0 * 576 + wseg * 8;
    const u16* Bbase = Wt + (size_t)col0 * 576 + wseg * 8;
    for (int ck = 0; ck < 18; ck++) {
        int k0 = ck * 32;
        #pragma unroll
        for (int i = 0; i < 2; i++) {
            int rr = (i * 4 + w) * 16 + wrow;
            *(uint4*)&As[rr * 40 + wseg * 8] = *(const uint4*)(Abase + (size_t)rr * 576 + k0);
            *(uint4*)&Bs[rr * 40 + wseg * 8] = *(const uint4*)(Bbase + (size_t)rr * 576 + k0);
        }
        __syncthreads();
        bf16x8 af[4], bfr[4];
        #pragma unroll
        for (int mt = 0; mt < 4; mt++)
            af[mt] = *(const bf16x8*)&As[(rh * 64 + mt * 16 + cc) * 40 + q * 8];
        #pragma unroll
        for (int nt = 0; nt < 4; nt++)
            bfr[nt] = *(const bf16x8*)&Bs[(ch * 64 + nt * 16 + cc) * 40 + q * 8];
        #pragma unroll
        for (int mt = 0; mt < 4; mt++)
            #pragma unroll
            for (int nt = 0; nt < 4; nt++)
                acc[mt][nt] = __builtin_amdgcn_mfma_f32_16x16x32_bf16(af[mt], bfr[nt], acc[mt][nt], 0, 0, 0);
        __syncthreads();
    }
    float hv[4], vv[4];
    #pragma unroll
    for (int nt = 0; nt < 4; nt++) {
        int n = col0 + ch * 64 + nt * 16 + cc;
        hv[nt] = hWa[b * ADIM + n];
        vv[nt] = Va[n];
    }
    #pragma unroll
    for (int mt = 0; mt < 4; mt++) {
        #pragma unroll
        for (int rr = 0; rr < 4; rr++) {
            float s = 0.f;
            #pragma unroll
            for (int nt = 0; nt < 4; nt++)
                s += fast_tanh(hv[nt] + acc[mt][nt][rr]) * vv[nt];
            s += __shfl_xor(s, 1, 16);
            s += __shfl_xor(s, 2, 16);
            s += __shfl_xor(s, 4, 16);
            s += __shfl_xor(s, 8, 16);
            if (cc == 0)
                atomicAdd(&e[row0 + rh * 64 + mt * 16 + q * 4 + rr], s);
        }
    }
}

// ---------------- softmax over L per batch ----------------
__global__ __launch_bounds__(256) void softmaxL_k(const float* __restrict__ e,
                                                  float* __restrict__ attn_ws,
                                                  float* __restrict__ attn_out) {
    int b = blockIdx.x, t = threadIdx.x;
    __shared__ float sm[4], ss[4];
    float v[8];
    float mx = -1e30f;
    #pragma unroll
    for (int i = 0; i < 8; i++) { v[i] = e[b * LSEQ + t + i * 256]; mx = fmaxf(mx, v[i]); }
    for (int o = 32; o; o >>= 1) mx = fmaxf(mx, __shfl_xor(mx, o, 64));
    if ((t & 63) == 0) sm[t >> 6] = mx;
    __syncthreads();
    mx = fmaxf(fmaxf(sm[0], sm[1]), fmaxf(sm[2], sm[3]));
    float s = 0.f;
    #pragma unroll
    for (int i = 0; i < 8; i++) { v[i] = __expf(v[i] - mx); s += v[i]; }
    for (int o = 32; o; o >>= 1) s += __shfl_xor(s, o, 64);
    if ((t & 63) == 0) ss[t >> 6] = s;
    __syncthreads();
    s = ss[0] + ss[1] + ss[2] + ss[3];
    float inv = 1.f / s;
    #pragma unroll
    for (int i = 0; i < 8; i++) {
        float p = v[i] * inv;
        attn_ws[b * LSEQ + t + i * 256] = p;
        attn_out[b * LSEQ + t + i * 256] = p;
    }
}

// ---------------- context = sum_l attn * feat (bf16 source), L-split atomics ----------------
__global__ __launch_bounds__(256) void context2_k(
    const u16* __restrict__ featbf, const float* __restrict__ attn,
    float* __restrict__ ctx)
{
    __shared__ float at[256];
    int t = threadIdx.x, b = blockIdx.y, lc = blockIdx.x;
    at[t] = attn[b * LSEQ + lc * 256 + t];
    __syncthreads();
    int col = t * 2;
    const u16* base = featbf + (size_t)(b * LSEQ + lc * 256) * 576 + col;
    float a0 = 0.f, a1 = 0.f;
    #pragma unroll 4
    for (int l = 0; l < 256; l++) {
        unsigned int u = *(const unsigned int*)(base + (size_t)l * 576);
        union { unsigned int i; float f; } lo, hi;
        lo.i = u << 16; hi.i = u & 0xffff0000u;
        float av = at[l];
        a0 += av * lo.f;
        a1 += av * hi.f;
    }
    atomicAdd(&ctx[b * UDIM + col], a0);
    atomicAdd(&ctx[b * UDIM + col + 1], a1);
}

// ---------------- softmax over V ----------------
__global__ __launch_bounds__(1024) void softmaxV_k(const float* __restrict__ logits,
                                                   float* __restrict__ out) {
    int b = blockIdx.x, t = threadIdx.x;
    __shared__ float sm[16], ss[16];
    const float* lp = logits + (size_t)b * VOC;
    float mx = -1e30f;
    for (int i = t; i < VOC; i += 1024) mx = fmaxf(mx, lp[i]);
    for (int o = 32; o; o >>= 1) mx = fmaxf(mx, __shfl_xor(mx, o, 64));
    if ((t & 63) == 0) sm[t >> 6] = mx;
    __syncthreads();
    if (t < 16) {
        float m2 = sm[t];
        for (int o = 8; o; o >>= 1) m2 = fmaxf(m2, __shfl_xor(m2, o, 16));
        sm[t] = m2;
    }
    __syncthreads();
    mx = sm[0];
    float s = 0.f;
    for (int i = t; i < VOC; i += 1024) s += __expf(lp[i] - mx);
    for (int o = 32; o; o >>= 1) s += __shfl_xor(s, o, 64);
    if ((t & 63) == 0) ss[t >> 6] = s;
    __syncthreads();
    if (t < 16) {
        float s2 = ss[t];
        for (int o = 8; o; o >>= 1) s2 += __shfl_xor(s2, o, 16);
        ss[t] = s2;
    }
    __syncthreads();
    float inv = 1.f / ss[0];
    float* op = out + (size_t)b * VOC;
    for (int i = t; i < VOC; i += 1024) op[i] = __expf(lp[i] - mx) * inv;
}

// ---------------- workspace layout (bytes) ----------------
#define OFF_FEATBF ((size_t)0)           // 150,994,944 (dead after context2_k; logits aliases)
#define OFF_WTCAT  ((size_t)150994944)
#define OFF_WTWA   ((size_t)151584768)
#define OFF_WTWE   ((size_t)152109056)
#define OFF_WTWO   ((size_t)168493056)
#define OFF_WTHC   ((size_t)184877056)
#define OFF_WTZ    ((size_t)185401344)
#define OFF_WTR    ((size_t)186712064)
#define OFF_WTH    ((size_t)188022784)
#define OFF_PTB    ((size_t)188809216)
#define OFF_PHB    ((size_t)192905216)
// zeroed region start
#define OFF_E      ((size_t)192970752)   // 524288
#define OFF_HWA    ((size_t)193495040)   // 131072
#define OFF_EY     ((size_t)193626112)   // 65536
#define OFF_CTX    ((size_t)193691648)   // 131072
#define OFF_ZTP    ((size_t)193822720)   // 131072
#define OFF_RTP    ((size_t)193953792)   // 131072
#define OFF_CCZ    ((size_t)194084864)   // 131072
#define OFF_HCP    ((size_t)194215936)   // 131072
// zeroed region end: 194347008 (1,376,256 B = 86016 float4)
#define OFF_ATTNWS ((size_t)194347008)   // 524288
#define OFF_GBF    ((size_t)194871296)   // 32768
#define OFF_LOGITS OFF_FEATBF

extern "C" void kernel_launch(void* const* d_in, const int* in_sizes, int n_in,
                              void* d_out, int out_size, void* d_ws, size_t ws_size,
                              hipStream_t stream)
{
    const float* prev_target = (const float*)d_in[0];
    const float* prev_hidden = (const float*)d_in[1];
    const float* features    = (const float*)d_in[2];
    const float* Bmat        = (const float*)d_in[3];
    const float* Wa    = (const float*)d_in[4];
    const float* Ua    = (const float*)d_in[5];
    const float* Va    = (const float*)d_in[6];
    const float* Uf    = (const float*)d_in[7];
    const float* Qk    = (const float*)d_in[8];
    const float* We    = (const float*)d_in[9];
    const float* Wccz  = (const float*)d_in[10];
    const float* Wyz   = (const float*)d_in[11];
    const float* Uhz   = (const float*)d_in[12];
    const float* Wyr   = (const float*)d_in[13];
    const float* Uhr   = (const float*)d_in[14];
    const float* Ccr   = (const float*)d_in[15];
    const float* Wyh   = (const float*)d_in[16];
    const float* b_wyh = (const float*)d_in[17];
    const float* Urh   = (const float*)d_in[18];
    const float* b_urh = (const float*)d_in[19];
    const float* Wo    = (const float*)d_in[20];
    const float* Wh    = (const float*)d_in[21];
    const float* Wc    = (const float*)d_in[22];

    char* w = (char*)d_ws;
    u16*   featbf  = (u16*)(w + OFF_FEATBF);
    u16*   Wt_cat  = (u16*)(w + OFF_WTCAT);
    u16*   Wt_wa   = (u16*)(w + OFF_WTWA);
    u16*   Wt_we   = (u16*)(w + OFF_WTWE);
    u16*   Wt_wo   = (u16*)(w + OFF_WTWO);
    u16*   Wt_hc   = (u16*)(w + OFF_WTHC);
    u16*   Wt_z    = (u16*)(w + OFF_WTZ);
    u16*   Wt_r    = (u16*)(w + OFF_WTR);
    u16*   Wt_h    = (u16*)(w + OFF_WTH);
    u16*   pt_bf   = (u16*)(w + OFF_PTB);
    u16*   ph_bf   = (u16*)(w + OFF_PHB);
    float* e_buf   = (float*)(w + OFF_E);
    float* hWa_buf = (float*)(w + OFF_HWA);
    float* Ey_buf  = (float*)(w + OFF_EY);
    float* ctx_buf = (float*)(w + OFF_CTX);
    float* ztp_buf = (float*)(w + OFF_ZTP);
    float* rtp_buf = (float*)(w + OFF_RTP);
    float* ccz_buf = (float*)(w + OFF_CCZ);
    float* hcp_buf = (float*)(w + OFF_HCP);
    float* attn_ws = (float*)(w + OFF_ATTNWS);
    u16*   Gbf     = (u16*)(w + OFF_GBF);
    float* logits  = (float*)(w + OFF_LOGITS);

    float* out      = (float*)d_out;
    float* ht_out   = out + (size_t)BZ * VOC;
    float* attn_out = ht_out + (size_t)BZ * UDIM;

    // ---- transpose jobs (Bt[n][k] = W[k][n]) ----
    TArgs ta;
    int cum = 0, ji = 0;
    auto addJob = [&](const float* src, u16* dst, int R, int C, int ld) {
        cum += (R / 32) * (C / 32);
        ta.j[ji].src = src; ta.j[ji].dst = dst;
        ta.j[ji].R = R; ta.j[ji].C = C; ta.j[ji].ld = ld; ta.j[ji].tileEnd = cum;
        ji++;
    };
    addJob(Ua,   Wt_cat + 0,   512, 512, 576);
    addJob(Uf,   Wt_cat + 512,  64, 512, 576);
    addJob(Wa,   Wt_wa,        512, 512, 512);
    addJob(We,   Wt_we,      32000, 256, 32000);
    addJob(Wo,   Wt_wo,        256, 32000, 256);
    addJob(Wh,   Wt_hc + 0,    512, 256, 1024);
    addJob(Wc,   Wt_hc + 512,  512, 256, 1024);
    addJob(Wyz,  Wt_z + 0,     256, 512, 1280);
    addJob(Uhz,  Wt_z + 256,   512, 512, 1280);
    addJob(Wccz, Wt_z + 768,   512, 512, 1280);
    addJob(Wyr,  Wt_r + 0,     256, 512, 1280);
    addJob(Uhr,  Wt_r + 256,   512, 512, 1280);
    addJob(Ccr,  Wt_r + 768,   512, 512, 1280);
    addJob(Wyh,  Wt_h + 0,     256, 512, 768);
    addJob(Urh,  Wt_h + 256,   512, 512, 768);
    ta.nj = ji;

    GAux aux;
    aux.Ey = Ey_buf; aux.h = prev_hidden; aux.ctx = ctx_buf;
    aux.rtp = rtp_buf; aux.ztp = ztp_buf; aux.hcp = hcp_buf; aux.ccz = ccz_buf;
    aux.bwyh = b_wyh; aux.burh = b_urh; aux.ht_out = ht_out;

    auto mkjob = [](const u16* A, int ldA, const u16* Bt, int ldB, float* C, int ldC,
                    int N, int K, int ckPer, int koff, int mode, int epi, int& c2) {
        GJob g; g.A = A; g.Bt = Bt; g.C = C; g.ldA = ldA; g.ldB = ldB; g.ldC = ldC;
        g.nT = N / 64; g.ckTot = K / 32; g.ckPer = ckPer;
        g.koff = koff; g.mode = mode; g.epi = epi;
        int ks = (g.ckTot + ckPer - 1) / ckPer;
        c2 += g.nT * ks; g.tileEnd = c2;
        return g;
    };

    // 1. zero accumulators (e..hcp)
    hipLaunchKernelGGL(zero_k, dim3(336), dim3(256), 0, stream, (float4*)e_buf, 86016);
    // 2. weight transposes
    hipLaunchKernelGGL(transpose_pack, dim3(cum), dim3(256), 0, stream, ta);
    // 3. pack prev_target / prev_hidden
    hipLaunchKernelGGL(pack_misc, dim3(8128), dim3(256), 0, stream,
                       prev_target, prev_hidden, pt_bf, ph_bf);
    // 4. features -> bf16 + fused conv
    hipLaunchKernelGGL(prep_feat_k, dim3(2048), dim3(256), 0, stream,
                       features, Bmat, Qk, featbf);
    // 5. batch A: hWa (store) + Ey (split-K atomic)
    {
        GArgs ga; ga.x = aux; int c2 = 0;
        ga.j[0] = mkjob(ph_bf, 512, Wt_wa, 512, hWa_buf, 512, 512, 512, 16, 0, 0, 1, c2);
        ga.j[1] = mkjob(pt_bf, 32000, Wt_we, 32000, Ey_buf, 256, 256, 32000, 20, 0, 0, 0, c2);
        hipLaunchKernelGGL(gemm_batch_k, dim3(c2), dim3(256), 0, stream, ga);
    }
    // 6. attention scores (XCD-swizzled 1D grid)
    hipLaunchKernelGGL(attn_gemm_k, dim3(4096), dim3(256), 0, stream,
                       featbf, Wt_cat, hWa_buf, Va, e_buf);
    // 7. softmax over L
    hipLaunchKernelGGL(softmaxL_k, dim3(64), dim3(256), 0, stream, e_buf, attn_ws, attn_out);
    // 8. context
    hipLaunchKernelGGL(context2_k, dim3(8, 64), dim3(256), 0, stream,
                       featbf, attn_ws, ctx_buf);
    // 9. batch B: ztp, rtp (K=1280, A=gen cat1), ccz (K=512, A=gen cat1 koff 768)
    {
        GArgs ga; ga.x = aux; int c2 = 0;
        ga.j[0] = mkjob(nullptr, 0, Wt_z, 1280, ztp_buf, 512, 512, 1280, 8, 0, 1, 0, c2);
        ga.j[1] = mkjob(nullptr, 0, Wt_r, 1280, rtp_buf, 512, 512, 1280, 8, 0, 1, 0, c2);
        ga.j[2] = mkjob(nullptr, 0, Wt_z + 768, 1280, ccz_buf, 512, 512, 512, 8, 768, 1, 0, c2);
        hipLaunchKernelGGL(gemm_batch_k, dim3(c2), dim3(256), 0, stream, ga);
    }
    // 10. batch C: hcp (K=768, A=gen [Ey|sig(rt)*h])
    {
        GArgs ga; ga.x = aux; int c2 = 0;
        ga.j[0] = mkjob(nullptr, 0, Wt_h, 768, hcp_buf, 512, 512, 768, 8, 0, 2, 0, c2);
        hipLaunchKernelGGL(gemm_batch_k, dim3(c2), dim3(256), 0, stream, ga);
    }
    // 11. batch D: Gbf = bf16(Ey + [ht|ctx]@[Wh;Wc]), non-split; writes ht_out on the fly
    {
        GArgs ga; ga.x = aux; int c2 = 0;
        ga.j[0] = mkjob(nullptr, 0, Wt_hc, 1024, (float*)Gbf, 256, 256, 1024, 32, 0, 3, 2, c2);
        hipLaunchKernelGGL(gemm_batch_k, dim3(c2), dim3(256), 0, stream, ga);
    }
    // 12. batch E: logits = Gbf @ Wo (K=256, store)
    {
        GArgs ga; ga.x = aux; int c2 = 0;
        ga.j[0] = mkjob(Gbf, 256, Wt_wo, 256, logits, 32000, 32000, 256, 8, 0, 0, 1, c2);
        hipLaunchKernelGGL(gemm_batch_k, dim3(c2), dim3(256), 0, stream, ga);
    }
    // 13. softmax over V
    hipLaunchKernelGGL(softmaxV_k, dim3(64), dim3(1024), 0, stream, logits, out);
}